// Round 5
// baseline (306.809 us; speedup 1.0000x reference)
//
#include <hip/hip_runtime.h>
#include <math.h>

#define DMODEL 1024
#define NHEAD  16
#define DK     64
#define BB     2
#define LL     2048
#define MTOT   (BB*LL)   // 4096

#define LOG2E      1.4426950408889634f
#define SCQ        (0.125f * LOG2E)    // folded into Q at projection epilogue
#define C2LOG      (0.1f * LOG2E)      // distance coeff in log2 domain

typedef __bf16 bf16_t;
typedef __bf16 bf16x8 __attribute__((ext_vector_type(8)));
typedef __bf16 bf16x4 __attribute__((ext_vector_type(4)));
typedef float  f32x4  __attribute__((ext_vector_type(4)));

static __device__ __forceinline__ f32x4 mfma16(bf16x8 a, bf16x8 b, f32x4 c) {
    return __builtin_amdgcn_mfma_f32_16x16x32_bf16(a, b, c, 0, 0, 0);
}
static __device__ __forceinline__ float exp2f_fast(float x) {
    return __builtin_amdgcn_exp2f(x);
}
static __device__ __forceinline__ float log2f_fast(float x) {
    return __builtin_amdgcn_logf(x);
}
// async global->LDS, 16B per lane. lds ptr must be wave-uniform; HW adds lane*16.
static __device__ __forceinline__ void gl_lds16(const bf16_t* g, bf16_t* l) {
    __builtin_amdgcn_global_load_lds(
        (const __attribute__((address_space(1))) unsigned int*)g,
        (__attribute__((address_space(3))) unsigned int*)l, 16, 0, 0);
}

// ---------------------------------------------------------------------------
// prep: x -> bf16; gid<MTOT also writes logd2 = log2(delta + 1e-6)
// ---------------------------------------------------------------------------
__global__ __launch_bounds__(256) void prep_x_k(
    const float* __restrict__ x, const float* __restrict__ dr,
    bf16_t* __restrict__ xb, float* __restrict__ logd2)
{
    size_t gid = (size_t)blockIdx.x * 256 + threadIdx.x;   // 524288 total
    size_t off = gid * 8;
    float4 a = *(const float4*)(x + off);
    float4 c = *(const float4*)(x + off + 4);
    float va[8] = {a.x, a.y, a.z, a.w, c.x, c.y, c.z, c.w};
    bf16x8 o1;
#pragma unroll
    for (int j = 0; j < 8; ++j) o1[j] = (bf16_t)va[j];
    *(bf16x8*)(xb + off) = o1;
    if (gid < MTOT) logd2[gid] = log2f_fast(dr[gid] + 1e-6f);
}

// ---------------------------------------------------------------------------
// prep: W[k][n] f32 -> Wt[n][k] bf16 (transpose + convert), 4 matrices by z.
// ---------------------------------------------------------------------------
__global__ __launch_bounds__(256) void prep_w_k(
    const float* __restrict__ Wq, const float* __restrict__ Wk,
    const float* __restrict__ Wv, const float* __restrict__ Wo,
    bf16_t* __restrict__ Wcat, bf16_t* __restrict__ Wot)
{
    __shared__ __align__(16) float Ts[64][68];
    const int z = blockIdx.z;
    const float* W = (z == 0) ? Wq : (z == 1) ? Wk : (z == 2) ? Wv : Wo;
    bf16_t* dst = (z < 3) ? (Wcat + (size_t)z * DMODEL * DMODEL) : Wot;
    const int tid = threadIdx.x;
    const int k0 = blockIdx.x * 64, n0 = blockIdx.y * 64;
#pragma unroll
    for (int i = 0; i < 4; ++i) {
        int u = tid + 256 * i, r = u >> 4, c4 = (u & 15) * 4;
        *(float4*)&Ts[r][c4] = *(const float4*)(W + (size_t)(k0 + r) * DMODEL + n0 + c4);
    }
    __syncthreads();
#pragma unroll
    for (int i = 0; i < 2; ++i) {
        int u = tid + 256 * i, n = u >> 3, k8 = (u & 7) * 8;
        bf16x8 v;
#pragma unroll
        for (int j = 0; j < 8; ++j) v[j] = (bf16_t)Ts[k8 + j][n];
        *(bf16x8*)(dst + (size_t)(n0 + n) * DMODEL + k0 + k8) = v;
    }
}

// ---------------------------------------------------------------------------
// 128x128 MFMA GEMM, BK=64, global_load_lds + XOR-swizzled LDS.
// mode 0 (N=3072): QKV epilogue. Q/K -> [b,h,l,dk] bf16 (Q pre-scaled SCQ);
//   V -> DIRECTLY TRANSPOSED Vt [b,h,dk,l] bf16 with delta row-scale.
// mode 1 (N=1024): outf[m][n] = acc + b0[n]  (f32)
// ---------------------------------------------------------------------------
__global__ __launch_bounds__(256, 3) void gemm128_k(
    const bf16_t* __restrict__ A, const bf16_t* __restrict__ Bt,
    const float* __restrict__ b0, const float* __restrict__ b1,
    const float* __restrict__ b2, const float* __restrict__ delta,
    float* __restrict__ outf, bf16_t* __restrict__ outQ,
    bf16_t* __restrict__ outK, bf16_t* __restrict__ outVt, int mode)
{
    __shared__ __align__(16) bf16_t Asw[128 * 64];
    __shared__ __align__(16) bf16_t Bsw[128 * 64];
    const int tid = threadIdx.x, lane = tid & 63, w = tid >> 6;
    const int quad = lane >> 4, n16 = lane & 15;
    const int wm = (w & 1) * 64, wn = (w >> 1) * 64;
    const int m0 = blockIdx.y * 128, n0 = blockIdx.x * 128;
    const int srow = lane >> 3;              // 0..7
    const int scb  = (lane & 7) ^ srow;      // swizzled col block this lane fetches

    f32x4 acc[4][4] = {};

    for (int K0 = 0; K0 < DMODEL; K0 += 64) {
        __syncthreads();
#pragma unroll
        for (int i = 0; i < 4; ++i) {
            int rb = w * 32 + i * 8;         // wave-uniform row base
            gl_lds16(A  + (size_t)(m0 + rb + srow) * DMODEL + K0 + scb * 8,
                     &Asw[rb * 64]);
            gl_lds16(Bt + (size_t)(n0 + rb + srow) * DMODEL + K0 + scb * 8,
                     &Bsw[rb * 64]);
        }
        __syncthreads();
#pragma unroll
        for (int kc = 0; kc < 2; ++kc) {
            const int pcb = ((kc * 4 + quad) ^ (n16 & 7)) * 8;
            bf16x8 af[4], bfv[4];
#pragma unroll
            for (int mi = 0; mi < 4; ++mi)
                af[mi] = *(const bf16x8*)&Asw[(wm + mi * 16 + n16) * 64 + pcb];
#pragma unroll
            for (int ni = 0; ni < 4; ++ni)
                bfv[ni] = *(const bf16x8*)&Bsw[(wn + ni * 16 + n16) * 64 + pcb];
#pragma unroll
            for (int mi = 0; mi < 4; ++mi)
#pragma unroll
                for (int ni = 0; ni < 4; ++ni)
                    acc[mi][ni] = mfma16(af[mi], bfv[ni], acc[mi][ni]);
        }
    }

    if (mode == 0) {
        const int region = n0 >> 10;         // uniform per block
        if (region == 2) {
            // V region: write transposed Vt[b,h,dk,l] with delta row-scale
#pragma unroll
            for (int mi = 0; mi < 4; ++mi) {
                const int mbase = m0 + wm + mi * 16 + quad * 4;  // 4 consecutive m
                const int bidx = mbase >> 11, l = mbase & (LL - 1);
                const f32x4 dm4 = *(const f32x4*)(delta + mbase);
#pragma unroll
                for (int ni = 0; ni < 4; ++ni) {
                    const int nl = (n0 & 1023) + wn + ni * 16 + n16;
                    const int h = nl >> 6, dd = nl & 63;
                    const float bv = b2[nl];
                    bf16x4 pk;
#pragma unroll
                    for (int r = 0; r < 4; ++r)
                        pk[r] = (bf16_t)(acc[mi][ni][r] * dm4[r] + bv);
                    *(bf16x4*)(outVt + ((size_t)(bidx * NHEAD + h) * DK + dd) * LL + l) = pk;
                }
            }
        } else {
            const float* bias = (region == 0) ? b0 : b1;
            bf16_t* dst = (region == 0) ? outQ : outK;
            const float qs = (region == 0) ? SCQ : 1.0f;
#pragma unroll
            for (int mi = 0; mi < 4; ++mi) {
#pragma unroll
                for (int r = 0; r < 4; ++r) {
                    const int m = m0 + wm + mi * 16 + quad * 4 + r;
                    const int bidx = m >> 11, l = m & (LL - 1);
#pragma unroll
                    for (int ni = 0; ni < 4; ++ni) {
                        const int nl = (n0 & 1023) + wn + ni * 16 + n16;
                        const int h = nl >> 6, dd = nl & 63;
                        float v = (acc[mi][ni][r] + bias[nl]) * qs;
                        dst[(((size_t)(bidx * NHEAD + h) * LL) + l) * DK + dd] = (bf16_t)v;
                    }
                }
            }
        }
    } else {
#pragma unroll
        for (int mi = 0; mi < 4; ++mi) {
#pragma unroll
            for (int r = 0; r < 4; ++r) {
                const int m = m0 + wm + mi * 16 + quad * 4 + r;
#pragma unroll
                for (int ni = 0; ni < 4; ++ni) {
                    const int n = n0 + wn + ni * 16 + n16;
                    outf[(size_t)m * DMODEL + n] = acc[mi][ni][r] + b0[n];
                }
            }
        }
    }
}

// ---------------------------------------------------------------------------
// MFMA flash attention, S^T formulation (exp2 domain), 128 q per block:
// 4 waves x 32 q (two 16-q MFMA column groups) -> each kb/vb LDS fragment
// feeds 2 MFMAs. Writes ctx bf16 and ml = m + log2(l).
// ---------------------------------------------------------------------------
__global__ __launch_bounds__(256, 2) void attn_flash_mfma_k(
    const bf16_t* __restrict__ Q, const bf16_t* __restrict__ K,
    const bf16_t* __restrict__ Vt, const float* __restrict__ logd2,
    bf16_t* __restrict__ ctx, float* __restrict__ mlout)
{
    __shared__ __align__(16) bf16_t Ks[64][72];
    __shared__ __align__(16) bf16_t Vts[64][72];   // [d][key]
    __shared__ __align__(16) bf16_t Ps[4][32][72]; // per-wave P, [q][k]
    __shared__ float logds[64];

    const int tid = threadIdx.x;
    const int lane = tid & 63, w = tid >> 6;
    const int quad = lane >> 4, n16 = lane & 15;
    const int bh = blockIdx.x, b = bh >> 4, h = bh & 15;
    const int q0 = blockIdx.y * 128;
    const size_t base = (size_t)bh * LL * DK;
    const int qq[2] = {q0 + w * 32 + n16, q0 + w * 32 + 16 + n16};

    // Q B-frags straight from global, kept for the whole kernel
    bf16x8 qa[2][2];
#pragma unroll
    for (int qg = 0; qg < 2; ++qg)
#pragma unroll
        for (int kc = 0; kc < 2; ++kc)
            qa[qg][kc] = *(const bf16x8*)(Q + base + (size_t)qq[qg] * DK +
                                          kc * 32 + quad * 8);

    const int strow = tid >> 3, stc8 = (tid & 7) * 8;   // staging: 32 rows/pass

    bf16x8 kr0, kr1, vr0, vr1;
    float ldr = 0.f;
    auto prefetch = [&](int k0) {
        kr0 = *(const bf16x8*)(K + base + (size_t)(k0 + strow) * DK + stc8);
        kr1 = *(const bf16x8*)(K + base + (size_t)(k0 + 32 + strow) * DK + stc8);
        vr0 = *(const bf16x8*)(Vt + base + (size_t)strow * LL + k0 + stc8);
        vr1 = *(const bf16x8*)(Vt + base + (size_t)(32 + strow) * LL + k0 + stc8);
        if (tid < 64) ldr = logd2[b * LL + k0 + tid];
    };

    float m_c[2] = {-1e30f, -1e30f}, l_c[2] = {0.f, 0.f};
    f32x4 o[2][4] = {};

    prefetch(0);
    for (int k0 = 0; k0 < LL; k0 += 64) {
        __syncthreads();
        *(bf16x8*)&Ks[strow][stc8]       = kr0;
        *(bf16x8*)&Ks[32 + strow][stc8]  = kr1;
        *(bf16x8*)&Vts[strow][stc8]      = vr0;
        *(bf16x8*)&Vts[32 + strow][stc8] = vr1;
        if (tid < 64) logds[tid] = ldr;
        __syncthreads();
        if (k0 + 64 < LL) prefetch(k0 + 64);

        // S^T tiles: s[qg][kt][r] = S[qq[qg]][k0 + kt*16 + quad*4 + r]
        f32x4 s[2][4] = {};
#pragma unroll
        for (int kc = 0; kc < 2; ++kc) {
#pragma unroll
            for (int kt = 0; kt < 4; ++kt) {
                bf16x8 kb = *(const bf16x8*)&Ks[kt * 16 + n16][kc * 32 + quad * 8];
                s[0][kt] = mfma16(kb, qa[0][kc], s[0][kt]);
                s[1][kt] = mfma16(kb, qa[1][kc], s[1][kt]);
            }
        }
        // bias (log2 domain)
#pragma unroll
        for (int qg = 0; qg < 2; ++qg) {
            const float df = (float)(qq[qg] - k0 - quad * 4);
#pragma unroll
            for (int kt = 0; kt < 4; ++kt) {
                f32x4 ldv = *(const f32x4*)&logds[kt * 16 + quad * 4];
#pragma unroll
                for (int r = 0; r < 4; ++r)
                    s[qg][kt][r] += ldv[r] - C2LOG * fabsf(df - (float)(kt * 16 + r));
            }
        }
        // per-lane online softmax (16 values in-register + 2 shfls per group)
        float mn[2], alpha[2];
#pragma unroll
        for (int qg = 0; qg < 2; ++qg) {
            f32x4 mx;
#pragma unroll
            for (int r = 0; r < 4; ++r)
                mx[r] = fmaxf(fmaxf(s[qg][0][r], s[qg][1][r]),
                              fmaxf(s[qg][2][r], s[qg][3][r]));
            float rm = fmaxf(fmaxf(mx[0], mx[1]), fmaxf(mx[2], mx[3]));
            rm = fmaxf(rm, __shfl_xor(rm, 16));
            rm = fmaxf(rm, __shfl_xor(rm, 32));
            mn[qg] = fmaxf(m_c[qg], rm);
            alpha[qg] = exp2f_fast(m_c[qg] - mn[qg]);
        }
        // skip o-rescale when no lane's max moved (alpha==1 exactly)
        if (__any((mn[0] > m_c[0]) || (mn[1] > m_c[1]))) {
#pragma unroll
            for (int qg = 0; qg < 2; ++qg)
#pragma unroll
                for (int dt = 0; dt < 4; ++dt)
#pragma unroll
                    for (int r = 0; r < 4; ++r) o[qg][dt][r] *= alpha[qg];
        }
#pragma unroll
        for (int qg = 0; qg < 2; ++qg) {
            f32x4 ps = {0.f, 0.f, 0.f, 0.f};
#pragma unroll
            for (int kt = 0; kt < 4; ++kt)
#pragma unroll
                for (int r = 0; r < 4; ++r) {
                    float p = exp2f_fast(s[qg][kt][r] - mn[qg]);
                    s[qg][kt][r] = p;
                    ps[r] += p;
                }
            float psum = (ps[0] + ps[1]) + (ps[2] + ps[3]);
            psum += __shfl_xor(psum, 16);
            psum += __shfl_xor(psum, 32);
            l_c[qg] = l_c[qg] * alpha[qg] + psum;
            m_c[qg] = mn[qg];
            // P pack: 4 consecutive k per kt -> b64 writes into [q][k]
#pragma unroll
            for (int kt = 0; kt < 4; ++kt) {
                bf16x4 pk;
#pragma unroll
                for (int r = 0; r < 4; ++r) pk[r] = (bf16_t)s[qg][kt][r];
                *(bf16x4*)&Ps[w][qg * 16 + n16][kt * 16 + quad * 4] = pk;
            }
        }
        __threadfence_block();
        // O^T += V^T P^T
#pragma unroll
        for (int kc = 0; kc < 2; ++kc) {
            bf16x8 pa0 = *(const bf16x8*)&Ps[w][n16][kc * 32 + quad * 8];
            bf16x8 pa1 = *(const bf16x8*)&Ps[w][16 + n16][kc * 32 + quad * 8];
#pragma unroll
            for (int dt = 0; dt < 4; ++dt) {
                bf16x8 vb = *(const bf16x8*)&Vts[dt * 16 + n16][kc * 32 + quad * 8];
                o[0][dt] = mfma16(vb, pa0, o[0][dt]);
                o[1][dt] = mfma16(vb, pa1, o[1][dt]);
            }
        }
    }
    // epilogue: lane owns q-columns; d = dt*16 + quad*4 + r -> packed b64 stores
#pragma unroll
    for (int qg = 0; qg < 2; ++qg) {
        const float inv = 1.f / l_c[qg];
#pragma unroll
        for (int dt = 0; dt < 4; ++dt) {
            bf16x4 ov;
#pragma unroll
            for (int r = 0; r < 4; ++r) ov[r] = (bf16_t)(o[qg][dt][r] * inv);
            *(bf16x4*)(ctx + ((size_t)b * LL + qq[qg]) * DMODEL + h * DK +
                       dt * 16 + quad * 4) = ov;
        }
        if (quad == 0)
            mlout[(size_t)bh * LL + qq[qg]] = m_c[qg] + log2f_fast(l_c[qg]);
    }
}

// ---------------------------------------------------------------------------
// attn.mean(heads), S^T formulation, 128 q per block: per block (b,128q,64k);
// loop heads, recompute S^T, normalize via stored ml. Dbuf K staging with
// register prefetch (1 barrier/head).
// ---------------------------------------------------------------------------
__global__ __launch_bounds__(256, 4) void attn_mean_mfma_k(
    const bf16_t* __restrict__ Q, const bf16_t* __restrict__ K,
    const float* __restrict__ logd2, const float* __restrict__ mlws,
    float* __restrict__ outmean)
{
    __shared__ __align__(16) bf16_t Ks[2][64][72];
    __shared__ float mls[2][128];
    __shared__ float logds[64];

    const int tid = threadIdx.x;
    const int lane = tid & 63, w = tid >> 6;
    const int quad = lane >> 4, n16 = lane & 15;
    const int k0 = blockIdx.x * 64, q0 = blockIdx.y * 128, b = blockIdx.z;
    const int qq[2] = {q0 + w * 32 + n16, q0 + w * 32 + 16 + n16};

    if (tid < 64) logds[tid] = logd2[b * LL + k0 + tid];

    const int strow = tid >> 3, stc8 = (tid & 7) * 8;

    bf16x8 kr0, kr1;
    float mlv = 0.f;
    auto load_head = [&](int h) {
        const size_t hb = (size_t)(b * NHEAD + h) * LL * DK;
        kr0 = *(const bf16x8*)(K + hb + (size_t)(k0 + strow) * DK + stc8);
        kr1 = *(const bf16x8*)(K + hb + (size_t)(k0 + 32 + strow) * DK + stc8);
        if (tid < 128) mlv = mlws[(size_t)(b * NHEAD + h) * LL + q0 + tid];
    };

    f32x4 acc[2][4] = {};

    load_head(0);
    for (int h = 0; h < NHEAD; ++h) {
        const int p = h & 1;
        *(bf16x8*)&Ks[p][strow][stc8]      = kr0;
        *(bf16x8*)&Ks[p][32 + strow][stc8] = kr1;
        if (tid < 128) mls[p][tid] = mlv;
        __syncthreads();
        if (h + 1 < NHEAD) load_head(h + 1);

        const size_t hb = (size_t)(b * NHEAD + h) * LL * DK;
        bf16x8 qan[2][2];
#pragma unroll
        for (int qg = 0; qg < 2; ++qg)
#pragma unroll
            for (int kc = 0; kc < 2; ++kc)
                qan[qg][kc] = *(const bf16x8*)(Q + hb + (size_t)qq[qg] * DK +
                                               kc * 32 + quad * 8);

        f32x4 s[2][4] = {};
#pragma unroll
        for (int kc = 0; kc < 2; ++kc) {
#pragma unroll
            for (int kt = 0; kt < 4; ++kt) {
                bf16x8 kb = *(const bf16x8*)&Ks[p][kt * 16 + n16][kc * 32 + quad * 8];
                s[0][kt] = mfma16(kb, qan[0][kc], s[0][kt]);
                s[1][kt] = mfma16(kb, qan[1][kc], s[1][kt]);
            }
        }
#pragma unroll
        for (int qg = 0; qg < 2; ++qg) {
            const float ml = mls[p][w * 32 + qg * 16 + n16];
            const float df = (float)(qq[qg] - k0 - quad * 4);
#pragma unroll
            for (int kt = 0; kt < 4; ++kt) {
                f32x4 ldv = *(const f32x4*)&logds[kt * 16 + quad * 4];
#pragma unroll
                for (int r = 0; r < 4; ++r) {
                    const float arg = s[qg][kt][r] + ldv[r]
                                    - C2LOG * fabsf(df - (float)(kt * 16 + r)) - ml;
                    acc[qg][kt][r] += exp2f_fast(arg);
                }
            }
        }
    }
    const float invH = 1.f / (float)NHEAD;
#pragma unroll
    for (int qg = 0; qg < 2; ++qg)
#pragma unroll
        for (int kt = 0; kt < 4; ++kt) {
            f32x4 ov;
#pragma unroll
            for (int r = 0; r < 4; ++r) ov[r] = acc[qg][kt][r] * invH;
            *(f32x4*)(outmean + ((size_t)b * LL + qq[qg]) * LL + k0 +
                      kt * 16 + quad * 4) = ov;
        }
}

// ---------------------------------------------------------------------------
extern "C" void kernel_launch(void* const* d_in, const int* in_sizes, int n_in,
                              void* d_out, int out_size, void* d_ws, size_t ws_size,
                              hipStream_t stream) {
    const float* x  = (const float*)d_in[0];
    const float* dr = (const float*)d_in[1];
    const float* Wq = (const float*)d_in[2];
    const float* bq = (const float*)d_in[3];
    const float* Wk = (const float*)d_in[4];
    const float* bk = (const float*)d_in[5];
    const float* Wv = (const float*)d_in[6];
    const float* bv = (const float*)d_in[7];
    const float* Wo = (const float*)d_in[8];
    const float* bo = (const float*)d_in[9];
    float* out = (float*)d_out;
    char* ws = (char*)d_ws;
    const size_t MB = 1ull << 20;

    bf16_t* xb   = (bf16_t*)(ws);             // 8 MB; reused as ctx after QKV gemm
    bf16_t* Wcat = (bf16_t*)(ws + 8 * MB);    // 6 MB  [3072][1024]
    bf16_t* Wot  = (bf16_t*)(ws + 14 * MB);   // 2 MB
    bf16_t* Qb   = (bf16_t*)(ws + 16 * MB);   // 8 MB
    bf16_t* Kb   = (bf16_t*)(ws + 24 * MB);   // 8 MB
    bf16_t* Vtb  = (bf16_t*)(ws + 32 * MB);   // 8 MB  [b,h,dk,l]
    float*  logd = (float*)(ws + 40 * MB);    // 16 KB
    float*  mlws = (float*)(ws + 41 * MB);    // 256 KB
    bf16_t* ctx  = xb;    // x dead after QKV projection

    prep_x_k<<<2048, 256, 0, stream>>>(x, dr, xb, logd);
    prep_w_k<<<dim3(16, 16, 4), 256, 0, stream>>>(Wq, Wk, Wv, Wo, Wcat, Wot);

    // fused QKV projection: N = 3072 (V written transposed, no vtrans pass)
    gemm128_k<<<dim3(24, 32), 256, 0, stream>>>(xb, Wcat, bq, bk, bv, dr,
                                                nullptr, Qb, Kb, Vtb, 0);

    // flash: grid (bh, qtile) so each head's K/V clusters on one XCD's L2
    attn_flash_mfma_k<<<dim3(32, 16), 256, 0, stream>>>(Qb, Kb, Vtb, logd,
                                                        ctx, mlws);
    attn_mean_mfma_k<<<dim3(32, 16, 2), 256, 0, stream>>>(Qb, Kb, logd, mlws,
                                                          out + (size_t)MTOT * DMODEL);
    // output projection
    gemm128_k<<<dim3(8, 32), 256, 0, stream>>>(ctx, Wot, bo, nullptr, nullptr,
                                               nullptr, out, nullptr, nullptr,
                                               nullptr, 1);
}

// Round 6
// 247.202 us; speedup vs baseline: 1.2411x; 1.2411x over previous
//
#include <hip/hip_runtime.h>
#include <math.h>

#define DMODEL 1024
#define NHEAD  16
#define DK     64
#define BB     2
#define LL     2048
#define MTOT   (BB*LL)   // 4096

#define LOG2E      1.4426950408889634f
#define SCQ        (0.125f * LOG2E)    // folded into Q at projection epilogue
#define C2LOG      (0.1f * LOG2E)      // distance coeff in log2 domain
#define SKIP_BOUND (-24.0f)            // skip tile if max log2(P) below this

typedef __bf16 bf16_t;
typedef __bf16 bf16x8 __attribute__((ext_vector_type(8)));
typedef __bf16 bf16x4 __attribute__((ext_vector_type(4)));
typedef float  f32x4  __attribute__((ext_vector_type(4)));

static __device__ __forceinline__ f32x4 mfma16(bf16x8 a, bf16x8 b, f32x4 c) {
    return __builtin_amdgcn_mfma_f32_16x16x32_bf16(a, b, c, 0, 0, 0);
}
static __device__ __forceinline__ float exp2f_fast(float x) {
    return __builtin_amdgcn_exp2f(x);
}
static __device__ __forceinline__ float log2f_fast(float x) {
    return __builtin_amdgcn_logf(x);
}
static __device__ __forceinline__ void gl_lds16(const bf16_t* g, bf16_t* l) {
    __builtin_amdgcn_global_load_lds(
        (const __attribute__((address_space(1))) unsigned int*)g,
        (__attribute__((address_space(3))) unsigned int*)l, 16, 0, 0);
}

// ---------------------------------------------------------------------------
// prep: x -> bf16; gid<MTOT also writes logd2 = log2(delta + 1e-6)
// ---------------------------------------------------------------------------
__global__ __launch_bounds__(256) void prep_x_k(
    const float* __restrict__ x, const float* __restrict__ dr,
    bf16_t* __restrict__ xb, float* __restrict__ logd2)
{
    size_t gid = (size_t)blockIdx.x * 256 + threadIdx.x;   // 524288 total
    size_t off = gid * 8;
    float4 a = *(const float4*)(x + off);
    float4 c = *(const float4*)(x + off + 4);
    float va[8] = {a.x, a.y, a.z, a.w, c.x, c.y, c.z, c.w};
    bf16x8 o1;
#pragma unroll
    for (int j = 0; j < 8; ++j) o1[j] = (bf16_t)va[j];
    *(bf16x8*)(xb + off) = o1;
    if (gid < MTOT) logd2[gid] = log2f_fast(dr[gid] + 1e-6f);
}

// ---------------------------------------------------------------------------
// prep: W[k][n] f32 -> Wt[n][k] bf16 (transpose + convert), 4 matrices by z.
// ---------------------------------------------------------------------------
__global__ __launch_bounds__(256) void prep_w_k(
    const float* __restrict__ Wq, const float* __restrict__ Wk,
    const float* __restrict__ Wv, const float* __restrict__ Wo,
    bf16_t* __restrict__ Wcat, bf16_t* __restrict__ Wot)
{
    __shared__ __align__(16) float Ts[64][68];
    const int z = blockIdx.z;
    const float* W = (z == 0) ? Wq : (z == 1) ? Wk : (z == 2) ? Wv : Wo;
    bf16_t* dst = (z < 3) ? (Wcat + (size_t)z * DMODEL * DMODEL) : Wot;
    const int tid = threadIdx.x;
    const int k0 = blockIdx.x * 64, n0 = blockIdx.y * 64;
#pragma unroll
    for (int i = 0; i < 4; ++i) {
        int u = tid + 256 * i, r = u >> 4, c4 = (u & 15) * 4;
        *(float4*)&Ts[r][c4] = *(const float4*)(W + (size_t)(k0 + r) * DMODEL + n0 + c4);
    }
    __syncthreads();
#pragma unroll
    for (int i = 0; i < 2; ++i) {
        int u = tid + 256 * i, n = u >> 3, k8 = (u & 7) * 8;
        bf16x8 v;
#pragma unroll
        for (int j = 0; j < 8; ++j) v[j] = (bf16_t)Ts[k8 + j][n];
        *(bf16x8*)(dst + (size_t)(n0 + n) * DMODEL + k0 + k8) = v;
    }
}

// ---------------------------------------------------------------------------
// 128x128 MFMA GEMM, BK=64, global_load_lds + XOR-swizzled LDS.
// mode 0 (N=3072): QKV epilogue (Q prescaled SCQ; V written transposed+scaled)
// mode 1 (N=1024): outf[m][n] = acc + b0[n]  (f32)
// ---------------------------------------------------------------------------
__global__ __launch_bounds__(256, 3) void gemm128_k(
    const bf16_t* __restrict__ A, const bf16_t* __restrict__ Bt,
    const float* __restrict__ b0, const float* __restrict__ b1,
    const float* __restrict__ b2, const float* __restrict__ delta,
    float* __restrict__ outf, bf16_t* __restrict__ outQ,
    bf16_t* __restrict__ outK, bf16_t* __restrict__ outVt, int mode)
{
    __shared__ __align__(16) bf16_t Asw[128 * 64];
    __shared__ __align__(16) bf16_t Bsw[128 * 64];
    const int tid = threadIdx.x, lane = tid & 63, w = tid >> 6;
    const int quad = lane >> 4, n16 = lane & 15;
    const int wm = (w & 1) * 64, wn = (w >> 1) * 64;
    const int m0 = blockIdx.y * 128, n0 = blockIdx.x * 128;
    const int srow = lane >> 3;
    const int scb  = (lane & 7) ^ srow;

    f32x4 acc[4][4] = {};

    for (int K0 = 0; K0 < DMODEL; K0 += 64) {
        __syncthreads();
#pragma unroll
        for (int i = 0; i < 4; ++i) {
            int rb = w * 32 + i * 8;
            gl_lds16(A  + (size_t)(m0 + rb + srow) * DMODEL + K0 + scb * 8,
                     &Asw[rb * 64]);
            gl_lds16(Bt + (size_t)(n0 + rb + srow) * DMODEL + K0 + scb * 8,
                     &Bsw[rb * 64]);
        }
        __syncthreads();
#pragma unroll
        for (int kc = 0; kc < 2; ++kc) {
            const int pcb = ((kc * 4 + quad) ^ (n16 & 7)) * 8;
            bf16x8 af[4], bfv[4];
#pragma unroll
            for (int mi = 0; mi < 4; ++mi)
                af[mi] = *(const bf16x8*)&Asw[(wm + mi * 16 + n16) * 64 + pcb];
#pragma unroll
            for (int ni = 0; ni < 4; ++ni)
                bfv[ni] = *(const bf16x8*)&Bsw[(wn + ni * 16 + n16) * 64 + pcb];
#pragma unroll
            for (int mi = 0; mi < 4; ++mi)
#pragma unroll
                for (int ni = 0; ni < 4; ++ni)
                    acc[mi][ni] = mfma16(af[mi], bfv[ni], acc[mi][ni]);
        }
    }

    if (mode == 0) {
        const int region = n0 >> 10;
        if (region == 2) {
#pragma unroll
            for (int mi = 0; mi < 4; ++mi) {
                const int mbase = m0 + wm + mi * 16 + quad * 4;
                const int bidx = mbase >> 11, l = mbase & (LL - 1);
                const f32x4 dm4 = *(const f32x4*)(delta + mbase);
#pragma unroll
                for (int ni = 0; ni < 4; ++ni) {
                    const int nl = (n0 & 1023) + wn + ni * 16 + n16;
                    const int h = nl >> 6, dd = nl & 63;
                    const float bv = b2[nl];
                    bf16x4 pk;
#pragma unroll
                    for (int r = 0; r < 4; ++r)
                        pk[r] = (bf16_t)(acc[mi][ni][r] * dm4[r] + bv);
                    *(bf16x4*)(outVt + ((size_t)(bidx * NHEAD + h) * DK + dd) * LL + l) = pk;
                }
            }
        } else {
            const float* bias = (region == 0) ? b0 : b1;
            bf16_t* dst = (region == 0) ? outQ : outK;
            const float qs = (region == 0) ? SCQ : 1.0f;
#pragma unroll
            for (int mi = 0; mi < 4; ++mi) {
#pragma unroll
                for (int r = 0; r < 4; ++r) {
                    const int m = m0 + wm + mi * 16 + quad * 4 + r;
                    const int bidx = m >> 11, l = m & (LL - 1);
#pragma unroll
                    for (int ni = 0; ni < 4; ++ni) {
                        const int nl = (n0 & 1023) + wn + ni * 16 + n16;
                        const int h = nl >> 6, dd = nl & 63;
                        float v = (acc[mi][ni][r] + bias[nl]) * qs;
                        dst[(((size_t)(bidx * NHEAD + h) * LL) + l) * DK + dd] = (bf16_t)v;
                    }
                }
            }
        }
    } else {
#pragma unroll
        for (int mi = 0; mi < 4; ++mi) {
#pragma unroll
            for (int r = 0; r < 4; ++r) {
                const int m = m0 + wm + mi * 16 + quad * 4 + r;
#pragma unroll
                for (int ni = 0; ni < 4; ++ni) {
                    const int n = n0 + wn + ni * 16 + n16;
                    outf[(size_t)m * DMODEL + n] = acc[mi][ni][r] + b0[n];
                }
            }
        }
    }
}

// ---------------------------------------------------------------------------
// stats: per (b,h): Qn[qtile16]=max||Q_row||, Kn[ktile32]=max||K_row||,
// dlb[qtile16]=min(diag QK + ld), ldx[b][ktile32]=max ld. All bounds for
// the sound tile-skip: s(q,k) <= ||q||*||k|| (Cauchy-Schwarz, log2 units).
// ---------------------------------------------------------------------------
__global__ __launch_bounds__(256) void stats_k(
    const bf16_t* __restrict__ Q, const bf16_t* __restrict__ K,
    const float* __restrict__ logd2, float* __restrict__ Qn,
    float* __restrict__ Kn, float* __restrict__ dlb, float* __restrict__ ldx)
{
    __shared__ float qn_s[2048], kn_s[2048], dg_s[2048];
    const int tid = threadIdx.x, bh = blockIdx.x, b = bh >> 4;
    const size_t base = (size_t)bh * LL * DK;
#pragma unroll
    for (int i = 0; i < 8; ++i) {
        const int row = tid + 256 * i;
        float qn2 = 0.f, kn2 = 0.f, dg = 0.f;
#pragma unroll
        for (int j = 0; j < 8; ++j) {
            bf16x8 qv = *(const bf16x8*)(Q + base + (size_t)row * DK + j * 8);
            bf16x8 kv = *(const bf16x8*)(K + base + (size_t)row * DK + j * 8);
#pragma unroll
            for (int e = 0; e < 8; ++e) {
                float fq = (float)qv[e], fk = (float)kv[e];
                qn2 += fq * fq; kn2 += fk * fk; dg += fq * fk;
            }
        }
        qn_s[row] = qn2;
        kn_s[row] = kn2;
        dg_s[row] = dg + logd2[b * LL + row];
    }
    __syncthreads();
    if (tid < 16) {
        float mq = 0.f, md = 1e30f;
        for (int r = 0; r < 128; ++r) {
            mq = fmaxf(mq, qn_s[tid * 128 + r]);
            md = fminf(md, dg_s[tid * 128 + r]);
        }
        Qn[bh * 16 + tid] = sqrtf(mq);
        dlb[bh * 16 + tid] = md;
    } else if (tid >= 64 && tid < 96) {
        const int t = tid - 64;
        float mk = 0.f;
        for (int r = 0; r < 64; ++r) mk = fmaxf(mk, kn_s[t * 64 + r]);
        Kn[bh * 32 + t] = sqrtf(mk);
    } else if (tid >= 128 && tid < 160 && (bh & 15) == 0) {
        const int t = tid - 128;
        float ml = -1e30f;
        for (int r = 0; r < 64; ++r) ml = fmaxf(ml, logd2[b * LL + t * 64 + r]);
        ldx[b * 32 + t] = ml;
    }
}

// ---------------------------------------------------------------------------
// mlmin[bh][qtile16] = min over 128 q of ml (after flash)
// ---------------------------------------------------------------------------
__global__ __launch_bounds__(256) void mlstat_k(
    const float* __restrict__ mlws, float* __restrict__ mlmin)
{
    __shared__ float s[2048];
    const int tid = threadIdx.x, bh = blockIdx.x;
#pragma unroll
    for (int i = 0; i < 8; ++i)
        s[tid + 256 * i] = mlws[(size_t)bh * LL + tid + 256 * i];
    __syncthreads();
    if (tid < 16) {
        float m = 1e30f;
        for (int r = 0; r < 128; ++r) m = fminf(m, s[tid * 128 + r]);
        mlmin[bh * 16 + tid] = m;
    }
}

// ---------------------------------------------------------------------------
// MFMA flash attention, S^T form, 128 q/block, sound far-tile skip.
// ml_final >= dlb (diagonal lower bound) makes the skip pre-flash-sound.
// ---------------------------------------------------------------------------
__global__ __launch_bounds__(256, 3) void attn_flash_mfma_k(
    const bf16_t* __restrict__ Q, const bf16_t* __restrict__ K,
    const bf16_t* __restrict__ Vt, const float* __restrict__ logd2,
    const float* __restrict__ Qn, const float* __restrict__ Kn,
    const float* __restrict__ dlb, const float* __restrict__ ldx,
    bf16_t* __restrict__ ctx, float* __restrict__ mlout)
{
    __shared__ __align__(16) bf16_t Ks[64][72];
    __shared__ __align__(16) bf16_t Vts[64][72];
    __shared__ __align__(16) bf16_t Ps[4][32][72];
    __shared__ float logds[64];

    const int tid = threadIdx.x;
    const int lane = tid & 63, w = tid >> 6;
    const int quad = lane >> 4, n16 = lane & 15;
    const int bh = blockIdx.x, b = bh >> 4, h = bh & 15;
    const int qt = blockIdx.y, q0 = qt * 128;
    const size_t base = (size_t)bh * LL * DK;
    const int qq[2] = {q0 + w * 32 + n16, q0 + w * 32 + 16 + n16};

    bf16x8 qa[2][2];
#pragma unroll
    for (int qg = 0; qg < 2; ++qg)
#pragma unroll
        for (int kc = 0; kc < 2; ++kc)
            qa[qg][kc] = *(const bf16x8*)(Q + base + (size_t)qq[qg] * DK +
                                          kc * 32 + quad * 8);

    // active-tile mask (block-uniform)
    unsigned mask = 0;
    {
        const float qn = Qn[bh * 16 + qt], dl = dlb[bh * 16 + qt];
        for (int t = 0; t < 32; ++t) {
            const int kc0 = t * 64;
            const int dmin = (kc0 > q0 + 127) ? (kc0 - (q0 + 127))
                           : ((q0 > kc0 + 63) ? (q0 - (kc0 + 63)) : 0);
            const float bound = qn * Kn[bh * 32 + t] + ldx[b * 32 + t]
                              - C2LOG * (float)dmin - dl;
            if (bound > SKIP_BOUND) mask |= (1u << t);
        }
    }

    const int strow = tid >> 3, stc8 = (tid & 7) * 8;
    bf16x8 kr0, kr1, vr0, vr1;
    float ldr = 0.f;
    auto prefetch = [&](int k0) {
        kr0 = *(const bf16x8*)(K + base + (size_t)(k0 + strow) * DK + stc8);
        kr1 = *(const bf16x8*)(K + base + (size_t)(k0 + 32 + strow) * DK + stc8);
        vr0 = *(const bf16x8*)(Vt + base + (size_t)strow * LL + k0 + stc8);
        vr1 = *(const bf16x8*)(Vt + base + (size_t)(32 + strow) * LL + k0 + stc8);
        if (tid < 64) ldr = logd2[b * LL + k0 + tid];
    };

    float m_c[2] = {-1e30f, -1e30f}, l_c[2] = {0.f, 0.f};
    f32x4 o[2][4] = {};

    int t = (int)__builtin_ctz(mask);   // mask != 0 guaranteed (diagonal)
    prefetch(t * 64);
    for (;;) {
        const unsigned rem = (t < 31) ? (mask >> (t + 1)) : 0u;
        const int tn = rem ? (t + 1 + (int)__builtin_ctz(rem)) : -1;
        __syncthreads();
        *(bf16x8*)&Ks[strow][stc8]       = kr0;
        *(bf16x8*)&Ks[32 + strow][stc8]  = kr1;
        *(bf16x8*)&Vts[strow][stc8]      = vr0;
        *(bf16x8*)&Vts[32 + strow][stc8] = vr1;
        if (tid < 64) logds[tid] = ldr;
        __syncthreads();
        if (tn >= 0) prefetch(tn * 64);
        const int k0 = t * 64;

        f32x4 s[2][4] = {};
#pragma unroll
        for (int kc = 0; kc < 2; ++kc) {
#pragma unroll
            for (int kt = 0; kt < 4; ++kt) {
                bf16x8 kb = *(const bf16x8*)&Ks[kt * 16 + n16][kc * 32 + quad * 8];
                s[0][kt] = mfma16(kb, qa[0][kc], s[0][kt]);
                s[1][kt] = mfma16(kb, qa[1][kc], s[1][kt]);
            }
        }
#pragma unroll
        for (int qg = 0; qg < 2; ++qg) {
            const float df = (float)(qq[qg] - k0 - quad * 4);
#pragma unroll
            for (int kt = 0; kt < 4; ++kt) {
                f32x4 ldv = *(const f32x4*)&logds[kt * 16 + quad * 4];
#pragma unroll
                for (int r = 0; r < 4; ++r)
                    s[qg][kt][r] += ldv[r] - C2LOG * fabsf(df - (float)(kt * 16 + r));
            }
        }
        float mn[2], alpha[2];
#pragma unroll
        for (int qg = 0; qg < 2; ++qg) {
            f32x4 mx;
#pragma unroll
            for (int r = 0; r < 4; ++r)
                mx[r] = fmaxf(fmaxf(s[qg][0][r], s[qg][1][r]),
                              fmaxf(s[qg][2][r], s[qg][3][r]));
            float rm = fmaxf(fmaxf(mx[0], mx[1]), fmaxf(mx[2], mx[3]));
            rm = fmaxf(rm, __shfl_xor(rm, 16));
            rm = fmaxf(rm, __shfl_xor(rm, 32));
            mn[qg] = fmaxf(m_c[qg], rm);
            alpha[qg] = exp2f_fast(m_c[qg] - mn[qg]);
        }
        if (__any((mn[0] > m_c[0]) || (mn[1] > m_c[1]))) {
#pragma unroll
            for (int qg = 0; qg < 2; ++qg)
#pragma unroll
                for (int dt = 0; dt < 4; ++dt)
#pragma unroll
                    for (int r = 0; r < 4; ++r) o[qg][dt][r] *= alpha[qg];
        }
#pragma unroll
        for (int qg = 0; qg < 2; ++qg) {
            f32x4 ps = {0.f, 0.f, 0.f, 0.f};
#pragma unroll
            for (int kt = 0; kt < 4; ++kt)
#pragma unroll
                for (int r = 0; r < 4; ++r) {
                    float p = exp2f_fast(s[qg][kt][r] - mn[qg]);
                    s[qg][kt][r] = p;
                    ps[r] += p;
                }
            float psum = (ps[0] + ps[1]) + (ps[2] + ps[3]);
            psum += __shfl_xor(psum, 16);
            psum += __shfl_xor(psum, 32);
            l_c[qg] = l_c[qg] * alpha[qg] + psum;
            m_c[qg] = mn[qg];
#pragma unroll
            for (int kt = 0; kt < 4; ++kt) {
                bf16x4 pk;
#pragma unroll
                for (int r = 0; r < 4; ++r) pk[r] = (bf16_t)s[qg][kt][r];
                *(bf16x4*)&Ps[w][qg * 16 + n16][kt * 16 + quad * 4] = pk;
            }
        }
        __threadfence_block();
#pragma unroll
        for (int kc = 0; kc < 2; ++kc) {
            bf16x8 pa0 = *(const bf16x8*)&Ps[w][n16][kc * 32 + quad * 8];
            bf16x8 pa1 = *(const bf16x8*)&Ps[w][16 + n16][kc * 32 + quad * 8];
#pragma unroll
            for (int dt = 0; dt < 4; ++dt) {
                bf16x8 vb = *(const bf16x8*)&Vts[dt * 16 + n16][kc * 32 + quad * 8];
                o[0][dt] = mfma16(vb, pa0, o[0][dt]);
                o[1][dt] = mfma16(vb, pa1, o[1][dt]);
            }
        }
        if (tn < 0) break;
        t = tn;
    }
#pragma unroll
    for (int qg = 0; qg < 2; ++qg) {
        const float inv = 1.f / l_c[qg];
#pragma unroll
        for (int dt = 0; dt < 4; ++dt) {
            bf16x4 ov;
#pragma unroll
            for (int r = 0; r < 4; ++r) ov[r] = (bf16_t)(o[qg][dt][r] * inv);
            *(bf16x4*)(ctx + ((size_t)b * LL + qq[qg]) * DMODEL + h * DK +
                       dt * 16 + quad * 4) = ov;
        }
        if (quad == 0)
            mlout[(size_t)bh * LL + qq[qg]] = m_c[qg] + log2f_fast(l_c[qg]);
    }
}

// ---------------------------------------------------------------------------
// attn.mean(heads), S^T form, 128 q/block, per-head skip + full prefetch.
// bias0 (head-invariant) hoisted out of the head loop.
// ---------------------------------------------------------------------------
__global__ __launch_bounds__(256, 3) void attn_mean_mfma_k(
    const bf16_t* __restrict__ Q, const bf16_t* __restrict__ K,
    const float* __restrict__ logd2, const float* __restrict__ mlws,
    const float* __restrict__ Qn, const float* __restrict__ Kn,
    const float* __restrict__ mlmin, const float* __restrict__ ldx,
    float* __restrict__ outmean)
{
    __shared__ __align__(16) bf16_t Ks[2][64][72];
    __shared__ float mls[2][128];
    __shared__ float logds[64];

    const int tid = threadIdx.x;
    const int lane = tid & 63, w = tid >> 6;
    const int quad = lane >> 4, n16 = lane & 15;
    const int k0 = blockIdx.x * 64, q0 = blockIdx.y * 128, b = blockIdx.z;
    const int qq[2] = {q0 + w * 32 + n16, q0 + w * 32 + 16 + n16};

    if (tid < 64) logds[tid] = logd2[b * LL + k0 + tid];
    __syncthreads();

    // head-invariant bias: logd(k) - C*|q-k|
    float bias0[2][4][4];
#pragma unroll
    for (int qg = 0; qg < 2; ++qg) {
        const float df = (float)(qq[qg] - k0 - quad * 4);
#pragma unroll
        for (int kt = 0; kt < 4; ++kt) {
            f32x4 ldv = *(const f32x4*)&logds[kt * 16 + quad * 4];
#pragma unroll
            for (int r = 0; r < 4; ++r)
                bias0[qg][kt][r] = ldv[r] - C2LOG * fabsf(df - (float)(kt * 16 + r));
        }
    }

    // per-head active mask (block-uniform)
    const int qt = q0 >> 7, ktl = k0 >> 6;
    const int dmin = (k0 > q0 + 127) ? (k0 - (q0 + 127))
                   : ((q0 > k0 + 63) ? (q0 - (k0 + 63)) : 0);
    unsigned hmask = 0;
    {
        const float dterm = ldx[b * 32 + ktl] - C2LOG * (float)dmin;
        for (int h = 0; h < NHEAD; ++h) {
            const int bh = b * 16 + h;
            const float bound = Qn[bh * 16 + qt] * Kn[bh * 32 + ktl] + dterm
                              - mlmin[bh * 16 + qt];
            if (bound > SKIP_BOUND) hmask |= (1u << h);
        }
    }

    f32x4 acc[2][4] = {};

    if (hmask) {
        const int strow = tid >> 3, stc8 = (tid & 7) * 8;
        bf16x8 kr0, kr1, qan[2][2];
        float mlv = 0.f;
        auto load_head = [&](int h) {
            const size_t hb = (size_t)(b * NHEAD + h) * LL * DK;
            kr0 = *(const bf16x8*)(K + hb + (size_t)(k0 + strow) * DK + stc8);
            kr1 = *(const bf16x8*)(K + hb + (size_t)(k0 + 32 + strow) * DK + stc8);
#pragma unroll
            for (int qg = 0; qg < 2; ++qg)
#pragma unroll
                for (int kc = 0; kc < 2; ++kc)
                    qan[qg][kc] = *(const bf16x8*)(Q + hb + (size_t)qq[qg] * DK +
                                                   kc * 32 + quad * 8);
            if (tid < 128) mlv = mlws[(size_t)(b * NHEAD + h) * LL + q0 + tid];
        };

        int h = (int)__builtin_ctz(hmask);
        load_head(h);
        int pc = 0;
        for (;;) {
            const unsigned rem = (h < 15) ? (hmask >> (h + 1)) : 0u;
            const int hn = rem ? (h + 1 + (int)__builtin_ctz(rem)) : -1;
            const int p = pc & 1;
            *(bf16x8*)&Ks[p][strow][stc8]      = kr0;
            *(bf16x8*)&Ks[p][32 + strow][stc8] = kr1;
            if (tid < 128) mls[p][tid] = mlv;
            bf16x8 qc[2][2] = {{qan[0][0], qan[0][1]}, {qan[1][0], qan[1][1]}};
            __syncthreads();
            if (hn >= 0) load_head(hn);

            f32x4 s[2][4] = {};
#pragma unroll
            for (int kc = 0; kc < 2; ++kc) {
#pragma unroll
                for (int kt = 0; kt < 4; ++kt) {
                    bf16x8 kb = *(const bf16x8*)&Ks[p][kt * 16 + n16][kc * 32 + quad * 8];
                    s[0][kt] = mfma16(kb, qc[0][kc], s[0][kt]);
                    s[1][kt] = mfma16(kb, qc[1][kc], s[1][kt]);
                }
            }
#pragma unroll
            for (int qg = 0; qg < 2; ++qg) {
                const float ml = mls[p][w * 32 + qg * 16 + n16];
#pragma unroll
                for (int kt = 0; kt < 4; ++kt)
#pragma unroll
                    for (int r = 0; r < 4; ++r)
                        acc[qg][kt][r] += exp2f_fast(s[qg][kt][r] +
                                                     bias0[qg][kt][r] - ml);
            }
            ++pc;
            if (hn < 0) break;
            h = hn;
        }
    }

    const float invH = 1.f / (float)NHEAD;
#pragma unroll
    for (int qg = 0; qg < 2; ++qg)
#pragma unroll
        for (int kt = 0; kt < 4; ++kt) {
            f32x4 ov;
#pragma unroll
            for (int r = 0; r < 4; ++r) ov[r] = acc[qg][kt][r] * invH;
            *(f32x4*)(outmean + ((size_t)b * LL + qq[qg]) * LL + k0 +
                      kt * 16 + quad * 4) = ov;
        }
}

// ---------------------------------------------------------------------------
extern "C" void kernel_launch(void* const* d_in, const int* in_sizes, int n_in,
                              void* d_out, int out_size, void* d_ws, size_t ws_size,
                              hipStream_t stream) {
    const float* x  = (const float*)d_in[0];
    const float* dr = (const float*)d_in[1];
    const float* Wq = (const float*)d_in[2];
    const float* bq = (const float*)d_in[3];
    const float* Wk = (const float*)d_in[4];
    const float* bk = (const float*)d_in[5];
    const float* Wv = (const float*)d_in[6];
    const float* bv = (const float*)d_in[7];
    const float* Wo = (const float*)d_in[8];
    const float* bo = (const float*)d_in[9];
    float* out = (float*)d_out;
    char* ws = (char*)d_ws;
    const size_t MB = 1ull << 20;

    bf16_t* xb   = (bf16_t*)(ws);             // 8 MB; reused as ctx after QKV gemm
    bf16_t* Wcat = (bf16_t*)(ws + 8 * MB);    // 6 MB  [3072][1024]
    bf16_t* Wot  = (bf16_t*)(ws + 14 * MB);   // 2 MB
    bf16_t* Qb   = (bf16_t*)(ws + 16 * MB);   // 8 MB
    bf16_t* Kb   = (bf16_t*)(ws + 24 * MB);   // 8 MB
    bf16_t* Vtb  = (bf16_t*)(ws + 32 * MB);   // 8 MB  [b,h,dk,l]
    float*  logd = (float*)(ws + 40 * MB);    // 16 KB
    float*  mlws = (float*)(ws + 41 * MB);    // 256 KB
    float*  Qns  = (float*)(ws + 42 * MB);            // [32][16]
    float*  Kns  = (float*)(ws + 42 * MB + 4096);     // [32][32]
    float*  dlb  = (float*)(ws + 42 * MB + 12288);    // [32][16]
    float*  ldxp = (float*)(ws + 42 * MB + 16384);    // [2][32]
    float*  mlmn = (float*)(ws + 42 * MB + 20480);    // [32][16]
    bf16_t* ctx  = xb;

    prep_x_k<<<2048, 256, 0, stream>>>(x, dr, xb, logd);
    prep_w_k<<<dim3(16, 16, 4), 256, 0, stream>>>(Wq, Wk, Wv, Wo, Wcat, Wot);

    gemm128_k<<<dim3(24, 32), 256, 0, stream>>>(xb, Wcat, bq, bk, bv, dr,
                                                nullptr, Qb, Kb, Vtb, 0);
    stats_k<<<32, 256, 0, stream>>>(Qb, Kb, logd, Qns, Kns, dlb, ldxp);

    attn_flash_mfma_k<<<dim3(32, 16), 256, 0, stream>>>(Qb, Kb, Vtb, logd,
                                                        Qns, Kns, dlb, ldxp,
                                                        ctx, mlws);
    mlstat_k<<<32, 256, 0, stream>>>(mlws, mlmn);
    attn_mean_mfma_k<<<dim3(32, 16, 2), 256, 0, stream>>>(
        Qb, Kb, logd, mlws, Qns, Kns, mlmn, ldxp,
        out + (size_t)MTOT * DMODEL);
    gemm128_k<<<dim3(8, 32), 256, 0, stream>>>(ctx, Wot, bo, nullptr, nullptr,
                                               nullptr, out, nullptr, nullptr,
                                               nullptr, 1);
}

// Round 7
// 242.973 us; speedup vs baseline: 1.2627x; 1.0174x over previous
//
#include <hip/hip_runtime.h>
#include <math.h>

#define DMODEL 1024
#define NHEAD  16
#define DK     64
#define BB     2
#define LL     2048
#define MTOT   (BB*LL)   // 4096

#define LOG2E      1.4426950408889634f
#define SCQ        (0.125f * LOG2E)    // folded into Q at projection epilogue
#define C2LOG      (0.1f * LOG2E)      // distance coeff in log2 domain
#define SKIP_BOUND (-24.0f)            // skip tile if max log2(P) below this

typedef __bf16 bf16_t;
typedef __bf16 bf16x8 __attribute__((ext_vector_type(8)));
typedef __bf16 bf16x4 __attribute__((ext_vector_type(4)));
typedef float  f32x4  __attribute__((ext_vector_type(4)));

static __device__ __forceinline__ f32x4 mfma16(bf16x8 a, bf16x8 b, f32x4 c) {
    return __builtin_amdgcn_mfma_f32_16x16x32_bf16(a, b, c, 0, 0, 0);
}
static __device__ __forceinline__ float exp2f_fast(float x) {
    return __builtin_amdgcn_exp2f(x);
}
static __device__ __forceinline__ float log2f_fast(float x) {
    return __builtin_amdgcn_logf(x);
}
static __device__ __forceinline__ void gl_lds16(const bf16_t* g, bf16_t* l) {
    __builtin_amdgcn_global_load_lds(
        (const __attribute__((address_space(1))) unsigned int*)g,
        (__attribute__((address_space(3))) unsigned int*)l, 16, 0, 0);
}

// ---------------------------------------------------------------------------
// prep: x -> bf16; gid<MTOT also writes logd2 = log2(delta + 1e-6)
// ---------------------------------------------------------------------------
__global__ __launch_bounds__(256) void prep_x_k(
    const float* __restrict__ x, const float* __restrict__ dr,
    bf16_t* __restrict__ xb, float* __restrict__ logd2)
{
    size_t gid = (size_t)blockIdx.x * 256 + threadIdx.x;   // 524288 total
    size_t off = gid * 8;
    float4 a = *(const float4*)(x + off);
    float4 c = *(const float4*)(x + off + 4);
    float va[8] = {a.x, a.y, a.z, a.w, c.x, c.y, c.z, c.w};
    bf16x8 o1;
#pragma unroll
    for (int j = 0; j < 8; ++j) o1[j] = (bf16_t)va[j];
    *(bf16x8*)(xb + off) = o1;
    if (gid < MTOT) logd2[gid] = log2f_fast(dr[gid] + 1e-6f);
}

// ---------------------------------------------------------------------------
// prep: W[k][n] f32 -> Wt[n][k] bf16 (transpose + convert), 4 matrices by z.
// ---------------------------------------------------------------------------
__global__ __launch_bounds__(256) void prep_w_k(
    const float* __restrict__ Wq, const float* __restrict__ Wk,
    const float* __restrict__ Wv, const float* __restrict__ Wo,
    bf16_t* __restrict__ Wcat, bf16_t* __restrict__ Wot)
{
    __shared__ __align__(16) float Ts[64][68];
    const int z = blockIdx.z;
    const float* W = (z == 0) ? Wq : (z == 1) ? Wk : (z == 2) ? Wv : Wo;
    bf16_t* dst = (z < 3) ? (Wcat + (size_t)z * DMODEL * DMODEL) : Wot;
    const int tid = threadIdx.x;
    const int k0 = blockIdx.x * 64, n0 = blockIdx.y * 64;
#pragma unroll
    for (int i = 0; i < 4; ++i) {
        int u = tid + 256 * i, r = u >> 4, c4 = (u & 15) * 4;
        *(float4*)&Ts[r][c4] = *(const float4*)(W + (size_t)(k0 + r) * DMODEL + n0 + c4);
    }
    __syncthreads();
#pragma unroll
    for (int i = 0; i < 2; ++i) {
        int u = tid + 256 * i, n = u >> 3, k8 = (u & 7) * 8;
        bf16x8 v;
#pragma unroll
        for (int j = 0; j < 8; ++j) v[j] = (bf16_t)Ts[k8 + j][n];
        *(bf16x8*)(dst + (size_t)(n0 + n) * DMODEL + k0 + k8) = v;
    }
}

// ---------------------------------------------------------------------------
// 128x128 MFMA GEMM, BK=64, global_load_lds + XOR-swizzled LDS.
// mode 0 (N=3072): QKV epilogue (Q prescaled SCQ; V written transposed+scaled)
// mode 1 (N=1024): outf[m][n] = acc + b0[n]  (f32)
// ---------------------------------------------------------------------------
__global__ __launch_bounds__(256, 3) void gemm128_k(
    const bf16_t* __restrict__ A, const bf16_t* __restrict__ Bt,
    const float* __restrict__ b0, const float* __restrict__ b1,
    const float* __restrict__ b2, const float* __restrict__ delta,
    float* __restrict__ outf, bf16_t* __restrict__ outQ,
    bf16_t* __restrict__ outK, bf16_t* __restrict__ outVt, int mode)
{
    __shared__ __align__(16) bf16_t Asw[128 * 64];
    __shared__ __align__(16) bf16_t Bsw[128 * 64];
    const int tid = threadIdx.x, lane = tid & 63, w = tid >> 6;
    const int quad = lane >> 4, n16 = lane & 15;
    const int wm = (w & 1) * 64, wn = (w >> 1) * 64;
    const int m0 = blockIdx.y * 128, n0 = blockIdx.x * 128;
    const int srow = lane >> 3;
    const int scb  = (lane & 7) ^ srow;

    f32x4 acc[4][4] = {};

    for (int K0 = 0; K0 < DMODEL; K0 += 64) {
        __syncthreads();
#pragma unroll
        for (int i = 0; i < 4; ++i) {
            int rb = w * 32 + i * 8;
            gl_lds16(A  + (size_t)(m0 + rb + srow) * DMODEL + K0 + scb * 8,
                     &Asw[rb * 64]);
            gl_lds16(Bt + (size_t)(n0 + rb + srow) * DMODEL + K0 + scb * 8,
                     &Bsw[rb * 64]);
        }
        __syncthreads();
#pragma unroll
        for (int kc = 0; kc < 2; ++kc) {
            const int pcb = ((kc * 4 + quad) ^ (n16 & 7)) * 8;
            bf16x8 af[4], bfv[4];
#pragma unroll
            for (int mi = 0; mi < 4; ++mi)
                af[mi] = *(const bf16x8*)&Asw[(wm + mi * 16 + n16) * 64 + pcb];
#pragma unroll
            for (int ni = 0; ni < 4; ++ni)
                bfv[ni] = *(const bf16x8*)&Bsw[(wn + ni * 16 + n16) * 64 + pcb];
#pragma unroll
            for (int mi = 0; mi < 4; ++mi)
#pragma unroll
                for (int ni = 0; ni < 4; ++ni)
                    acc[mi][ni] = mfma16(af[mi], bfv[ni], acc[mi][ni]);
        }
    }

    if (mode == 0) {
        const int region = n0 >> 10;
        if (region == 2) {
#pragma unroll
            for (int mi = 0; mi < 4; ++mi) {
                const int mbase = m0 + wm + mi * 16 + quad * 4;
                const int bidx = mbase >> 11, l = mbase & (LL - 1);
                const f32x4 dm4 = *(const f32x4*)(delta + mbase);
#pragma unroll
                for (int ni = 0; ni < 4; ++ni) {
                    const int nl = (n0 & 1023) + wn + ni * 16 + n16;
                    const int h = nl >> 6, dd = nl & 63;
                    const float bv = b2[nl];
                    bf16x4 pk;
#pragma unroll
                    for (int r = 0; r < 4; ++r)
                        pk[r] = (bf16_t)(acc[mi][ni][r] * dm4[r] + bv);
                    *(bf16x4*)(outVt + ((size_t)(bidx * NHEAD + h) * DK + dd) * LL + l) = pk;
                }
            }
        } else {
            const float* bias = (region == 0) ? b0 : b1;
            bf16_t* dst = (region == 0) ? outQ : outK;
            const float qs = (region == 0) ? SCQ : 1.0f;
#pragma unroll
            for (int mi = 0; mi < 4; ++mi) {
#pragma unroll
                for (int r = 0; r < 4; ++r) {
                    const int m = m0 + wm + mi * 16 + quad * 4 + r;
                    const int bidx = m >> 11, l = m & (LL - 1);
#pragma unroll
                    for (int ni = 0; ni < 4; ++ni) {
                        const int nl = (n0 & 1023) + wn + ni * 16 + n16;
                        const int h = nl >> 6, dd = nl & 63;
                        float v = (acc[mi][ni][r] + bias[nl]) * qs;
                        dst[(((size_t)(bidx * NHEAD + h) * LL) + l) * DK + dd] = (bf16_t)v;
                    }
                }
            }
        }
    } else {
#pragma unroll
        for (int mi = 0; mi < 4; ++mi) {
#pragma unroll
            for (int r = 0; r < 4; ++r) {
                const int m = m0 + wm + mi * 16 + quad * 4 + r;
#pragma unroll
                for (int ni = 0; ni < 4; ++ni) {
                    const int n = n0 + wn + ni * 16 + n16;
                    outf[(size_t)m * DMODEL + n] = acc[mi][ni][r] + b0[n];
                }
            }
        }
    }
}

// ---------------------------------------------------------------------------
// 64x128 MFMA GEMM for the output projection (more blocks -> occupancy).
// outf[m][n] = acc + b0[n]  (f32). Wave: 32m x 64n.
// ---------------------------------------------------------------------------
__global__ __launch_bounds__(256, 4) void gemm_out_k(
    const bf16_t* __restrict__ A, const bf16_t* __restrict__ Bt,
    const float* __restrict__ b0, float* __restrict__ outf)
{
    __shared__ __align__(16) bf16_t Asw[64 * 64];
    __shared__ __align__(16) bf16_t Bsw[128 * 64];
    const int tid = threadIdx.x, lane = tid & 63, w = tid >> 6;
    const int quad = lane >> 4, n16 = lane & 15;
    const int wm = (w & 1) * 32, wn = (w >> 1) * 64;
    const int m0 = blockIdx.y * 64, n0 = blockIdx.x * 128;
    const int srow = lane >> 3;
    const int scb  = (lane & 7) ^ srow;

    f32x4 acc[2][4] = {};

    for (int K0 = 0; K0 < DMODEL; K0 += 64) {
        __syncthreads();
#pragma unroll
        for (int i = 0; i < 2; ++i) {
            int rb = w * 16 + i * 8;
            gl_lds16(A + (size_t)(m0 + rb + srow) * DMODEL + K0 + scb * 8,
                     &Asw[rb * 64]);
        }
#pragma unroll
        for (int i = 0; i < 4; ++i) {
            int rb = w * 32 + i * 8;
            gl_lds16(Bt + (size_t)(n0 + rb + srow) * DMODEL + K0 + scb * 8,
                     &Bsw[rb * 64]);
        }
        __syncthreads();
#pragma unroll
        for (int kc = 0; kc < 2; ++kc) {
            const int pcb = ((kc * 4 + quad) ^ (n16 & 7)) * 8;
            bf16x8 af[2], bfv[4];
#pragma unroll
            for (int mi = 0; mi < 2; ++mi)
                af[mi] = *(const bf16x8*)&Asw[(wm + mi * 16 + n16) * 64 + pcb];
#pragma unroll
            for (int ni = 0; ni < 4; ++ni)
                bfv[ni] = *(const bf16x8*)&Bsw[(wn + ni * 16 + n16) * 64 + pcb];
#pragma unroll
            for (int mi = 0; mi < 2; ++mi)
#pragma unroll
                for (int ni = 0; ni < 4; ++ni)
                    acc[mi][ni] = mfma16(af[mi], bfv[ni], acc[mi][ni]);
        }
    }
#pragma unroll
    for (int mi = 0; mi < 2; ++mi) {
#pragma unroll
        for (int r = 0; r < 4; ++r) {
            const int m = m0 + wm + mi * 16 + quad * 4 + r;
#pragma unroll
            for (int ni = 0; ni < 4; ++ni) {
                const int n = n0 + wn + ni * 16 + n16;
                outf[(size_t)m * DMODEL + n] = acc[mi][ni][r] + b0[n];
            }
        }
    }
}

// ---------------------------------------------------------------------------
// stats: per (b,h): Qn[qtile16]=max||Q_row||, Kn[ktile32]=max||K_row||,
// dlb[qtile16]=min(diag QK + ld), ldx[b][ktile32]=max ld.
// ---------------------------------------------------------------------------
__global__ __launch_bounds__(256) void stats_k(
    const bf16_t* __restrict__ Q, const bf16_t* __restrict__ K,
    const float* __restrict__ logd2, float* __restrict__ Qn,
    float* __restrict__ Kn, float* __restrict__ dlb, float* __restrict__ ldx)
{
    __shared__ float qn_s[2048], kn_s[2048], dg_s[2048];
    const int tid = threadIdx.x, bh = blockIdx.x, b = bh >> 4;
    const size_t base = (size_t)bh * LL * DK;
#pragma unroll
    for (int i = 0; i < 8; ++i) {
        const int row = tid + 256 * i;
        float qn2 = 0.f, kn2 = 0.f, dg = 0.f;
#pragma unroll
        for (int j = 0; j < 8; ++j) {
            bf16x8 qv = *(const bf16x8*)(Q + base + (size_t)row * DK + j * 8);
            bf16x8 kv = *(const bf16x8*)(K + base + (size_t)row * DK + j * 8);
#pragma unroll
            for (int e = 0; e < 8; ++e) {
                float fq = (float)qv[e], fk = (float)kv[e];
                qn2 += fq * fq; kn2 += fk * fk; dg += fq * fk;
            }
        }
        qn_s[row] = qn2;
        kn_s[row] = kn2;
        dg_s[row] = dg + logd2[b * LL + row];
    }
    __syncthreads();
    if (tid < 16) {
        float mq = 0.f, md = 1e30f;
        for (int r = 0; r < 128; ++r) {
            mq = fmaxf(mq, qn_s[tid * 128 + r]);
            md = fminf(md, dg_s[tid * 128 + r]);
        }
        Qn[bh * 16 + tid] = sqrtf(mq);
        dlb[bh * 16 + tid] = md;
    } else if (tid >= 64 && tid < 96) {
        const int t = tid - 64;
        float mk = 0.f;
        for (int r = 0; r < 64; ++r) mk = fmaxf(mk, kn_s[t * 64 + r]);
        Kn[bh * 32 + t] = sqrtf(mk);
    } else if (tid >= 128 && tid < 160 && (bh & 15) == 0) {
        const int t = tid - 128;
        float ml = -1e30f;
        for (int r = 0; r < 64; ++r) ml = fmaxf(ml, logd2[b * LL + t * 64 + r]);
        ldx[b * 32 + t] = ml;
    }
}

// ---------------------------------------------------------------------------
// mlmin[bh][qtile16] = min over 128 q of ml (after flash)
// ---------------------------------------------------------------------------
__global__ __launch_bounds__(256) void mlstat_k(
    const float* __restrict__ mlws, float* __restrict__ mlmin)
{
    __shared__ float s[2048];
    const int tid = threadIdx.x, bh = blockIdx.x;
#pragma unroll
    for (int i = 0; i < 8; ++i)
        s[tid + 256 * i] = mlws[(size_t)bh * LL + tid + 256 * i];
    __syncthreads();
    if (tid < 16) {
        float m = 1e30f;
        for (int r = 0; r < 128; ++r) m = fminf(m, s[tid * 128 + r]);
        mlmin[bh * 16 + tid] = m;
    }
}

// ---------------------------------------------------------------------------
// MFMA flash attention, S^T form, 64 q/block (1024 blocks -> 16 waves/CU),
// sound far-tile skip (stats indexed by 128-q supertile: still sound bounds).
// ---------------------------------------------------------------------------
__global__ __launch_bounds__(256, 4) void attn_flash_mfma_k(
    const bf16_t* __restrict__ Q, const bf16_t* __restrict__ K,
    const bf16_t* __restrict__ Vt, const float* __restrict__ logd2,
    const float* __restrict__ Qn, const float* __restrict__ Kn,
    const float* __restrict__ dlb, const float* __restrict__ ldx,
    bf16_t* __restrict__ ctx, float* __restrict__ mlout)
{
    __shared__ __align__(16) bf16_t Ks[64][72];
    __shared__ __align__(16) bf16_t Vts[64][72];
    __shared__ __align__(16) bf16_t Ps[4][16][72];
    __shared__ float logds[64];

    const int tid = threadIdx.x;
    const int lane = tid & 63, w = tid >> 6;
    const int quad = lane >> 4, n16 = lane & 15;
    const int bh = blockIdx.x, b = bh >> 4, h = bh & 15;
    const int qt = blockIdx.y, q0 = qt * 64;
    const size_t base = (size_t)bh * LL * DK;
    const int q = q0 + w * 16 + n16;

    bf16x8 qa[2];
#pragma unroll
    for (int kc = 0; kc < 2; ++kc)
        qa[kc] = *(const bf16x8*)(Q + base + (size_t)q * DK + kc * 32 + quad * 8);

    // active-tile mask (block-uniform); stats are per 128-q supertile
    unsigned mask = 0;
    {
        const float qn = Qn[bh * 16 + (qt >> 1)], dl = dlb[bh * 16 + (qt >> 1)];
        for (int t = 0; t < 32; ++t) {
            const int kc0 = t * 64;
            const int dmin = (kc0 > q0 + 63) ? (kc0 - (q0 + 63))
                           : ((q0 > kc0 + 63) ? (q0 - (kc0 + 63)) : 0);
            const float bound = qn * Kn[bh * 32 + t] + ldx[b * 32 + t]
                              - C2LOG * (float)dmin - dl;
            if (bound > SKIP_BOUND) mask |= (1u << t);
        }
    }

    const int strow = tid >> 3, stc8 = (tid & 7) * 8;
    bf16x8 kr0, kr1, vr0, vr1;
    float ldr = 0.f;
    auto prefetch = [&](int k0) {
        kr0 = *(const bf16x8*)(K + base + (size_t)(k0 + strow) * DK + stc8);
        kr1 = *(const bf16x8*)(K + base + (size_t)(k0 + 32 + strow) * DK + stc8);
        vr0 = *(const bf16x8*)(Vt + base + (size_t)strow * LL + k0 + stc8);
        vr1 = *(const bf16x8*)(Vt + base + (size_t)(32 + strow) * LL + k0 + stc8);
        if (tid < 64) ldr = logd2[b * LL + k0 + tid];
    };

    float m_c = -1e30f, l_c = 0.f;
    f32x4 o[4] = {};
    const float dfq = (float)(q - quad * 4);

    int t = (int)__builtin_ctz(mask);   // mask != 0 guaranteed (diagonal)
    prefetch(t * 64);
    for (;;) {
        const unsigned rem = (t < 31) ? (mask >> (t + 1)) : 0u;
        const int tn = rem ? (t + 1 + (int)__builtin_ctz(rem)) : -1;
        __syncthreads();
        *(bf16x8*)&Ks[strow][stc8]       = kr0;
        *(bf16x8*)&Ks[32 + strow][stc8]  = kr1;
        *(bf16x8*)&Vts[strow][stc8]      = vr0;
        *(bf16x8*)&Vts[32 + strow][stc8] = vr1;
        if (tid < 64) logds[tid] = ldr;
        __syncthreads();
        if (tn >= 0) prefetch(tn * 64);
        const int k0 = t * 64;

        f32x4 s[4] = {};
#pragma unroll
        for (int kc = 0; kc < 2; ++kc) {
#pragma unroll
            for (int kt = 0; kt < 4; ++kt) {
                bf16x8 kb = *(const bf16x8*)&Ks[kt * 16 + n16][kc * 32 + quad * 8];
                s[kt] = mfma16(kb, qa[kc], s[kt]);
            }
        }
        const float df = dfq - (float)k0;
#pragma unroll
        for (int kt = 0; kt < 4; ++kt) {
            f32x4 ldv = *(const f32x4*)&logds[kt * 16 + quad * 4];
#pragma unroll
            for (int r = 0; r < 4; ++r)
                s[kt][r] += ldv[r] - C2LOG * fabsf(df - (float)(kt * 16 + r));
        }
        f32x4 mx;
#pragma unroll
        for (int r = 0; r < 4; ++r)
            mx[r] = fmaxf(fmaxf(s[0][r], s[1][r]), fmaxf(s[2][r], s[3][r]));
        float rm = fmaxf(fmaxf(mx[0], mx[1]), fmaxf(mx[2], mx[3]));
        rm = fmaxf(rm, __shfl_xor(rm, 16));
        rm = fmaxf(rm, __shfl_xor(rm, 32));
        const float mn = fmaxf(m_c, rm);
        const float alpha = exp2f_fast(m_c - mn);
        if (__any(mn > m_c)) {
#pragma unroll
            for (int dt = 0; dt < 4; ++dt)
#pragma unroll
                for (int r = 0; r < 4; ++r) o[dt][r] *= alpha;
        }
        f32x4 ps = {0.f, 0.f, 0.f, 0.f};
#pragma unroll
        for (int kt = 0; kt < 4; ++kt)
#pragma unroll
            for (int r = 0; r < 4; ++r) {
                float p = exp2f_fast(s[kt][r] - mn);
                s[kt][r] = p;
                ps[r] += p;
            }
        float psum = (ps[0] + ps[1]) + (ps[2] + ps[3]);
        psum += __shfl_xor(psum, 16);
        psum += __shfl_xor(psum, 32);
        l_c = l_c * alpha + psum;
        m_c = mn;
#pragma unroll
        for (int kt = 0; kt < 4; ++kt) {
            bf16x4 pk;
#pragma unroll
            for (int r = 0; r < 4; ++r) pk[r] = (bf16_t)s[kt][r];
            *(bf16x4*)&Ps[w][n16][kt * 16 + quad * 4] = pk;
        }
        __threadfence_block();
#pragma unroll
        for (int kc = 0; kc < 2; ++kc) {
            bf16x8 pa = *(const bf16x8*)&Ps[w][n16][kc * 32 + quad * 8];
#pragma unroll
            for (int dt = 0; dt < 4; ++dt) {
                bf16x8 vb = *(const bf16x8*)&Vts[dt * 16 + n16][kc * 32 + quad * 8];
                o[dt] = mfma16(vb, pa, o[dt]);
            }
        }
        if (tn < 0) break;
        t = tn;
    }
    const float inv = 1.f / l_c;
#pragma unroll
    for (int dt = 0; dt < 4; ++dt) {
        bf16x4 ov;
#pragma unroll
        for (int r = 0; r < 4; ++r) ov[r] = (bf16_t)(o[dt][r] * inv);
        *(bf16x4*)(ctx + ((size_t)b * LL + q) * DMODEL + h * DK +
                   dt * 16 + quad * 4) = ov;
    }
    if (quad == 0)
        mlout[(size_t)bh * LL + q] = m_c + log2f_fast(l_c);
}

// ---------------------------------------------------------------------------
// attn.mean(heads), S^T form, 128 q/block, per-head skip + full prefetch.
// ---------------------------------------------------------------------------
__global__ __launch_bounds__(256, 3) void attn_mean_mfma_k(
    const bf16_t* __restrict__ Q, const bf16_t* __restrict__ K,
    const float* __restrict__ logd2, const float* __restrict__ mlws,
    const float* __restrict__ Qn, const float* __restrict__ Kn,
    const float* __restrict__ mlmin, const float* __restrict__ ldx,
    float* __restrict__ outmean)
{
    __shared__ __align__(16) bf16_t Ks[2][64][72];
    __shared__ float mls[2][128];
    __shared__ float logds[64];

    const int tid = threadIdx.x;
    const int lane = tid & 63, w = tid >> 6;
    const int quad = lane >> 4, n16 = lane & 15;
    const int k0 = blockIdx.x * 64, q0 = blockIdx.y * 128, b = blockIdx.z;
    const int qq[2] = {q0 + w * 32 + n16, q0 + w * 32 + 16 + n16};

    if (tid < 64) logds[tid] = logd2[b * LL + k0 + tid];
    __syncthreads();

    float bias0[2][4][4];
#pragma unroll
    for (int qg = 0; qg < 2; ++qg) {
        const float df = (float)(qq[qg] - k0 - quad * 4);
#pragma unroll
        for (int kt = 0; kt < 4; ++kt) {
            f32x4 ldv = *(const f32x4*)&logds[kt * 16 + quad * 4];
#pragma unroll
            for (int r = 0; r < 4; ++r)
                bias0[qg][kt][r] = ldv[r] - C2LOG * fabsf(df - (float)(kt * 16 + r));
        }
    }

    const int qt = q0 >> 7, ktl = k0 >> 6;
    const int dmin = (k0 > q0 + 127) ? (k0 - (q0 + 127))
                   : ((q0 > k0 + 63) ? (q0 - (k0 + 63)) : 0);
    unsigned hmask = 0;
    {
        const float dterm = ldx[b * 32 + ktl] - C2LOG * (float)dmin;
        for (int h = 0; h < NHEAD; ++h) {
            const int bh = b * 16 + h;
            const float bound = Qn[bh * 16 + qt] * Kn[bh * 32 + ktl] + dterm
                              - mlmin[bh * 16 + qt];
            if (bound > SKIP_BOUND) hmask |= (1u << h);
        }
    }

    f32x4 acc[2][4] = {};

    if (hmask) {
        const int strow = tid >> 3, stc8 = (tid & 7) * 8;
        bf16x8 kr0, kr1, qan[2][2];
        float mlv = 0.f;
        auto load_head = [&](int h) {
            const size_t hb = (size_t)(b * NHEAD + h) * LL * DK;
            kr0 = *(const bf16x8*)(K + hb + (size_t)(k0 + strow) * DK + stc8);
            kr1 = *(const bf16x8*)(K + hb + (size_t)(k0 + 32 + strow) * DK + stc8);
#pragma unroll
            for (int qg = 0; qg < 2; ++qg)
#pragma unroll
                for (int kc = 0; kc < 2; ++kc)
                    qan[qg][kc] = *(const bf16x8*)(Q + hb + (size_t)qq[qg] * DK +
                                                   kc * 32 + quad * 8);
            if (tid < 128) mlv = mlws[(size_t)(b * NHEAD + h) * LL + q0 + tid];
        };

        int h = (int)__builtin_ctz(hmask);
        load_head(h);
        int pc = 0;
        for (;;) {
            const unsigned rem = (h < 15) ? (hmask >> (h + 1)) : 0u;
            const int hn = rem ? (h + 1 + (int)__builtin_ctz(rem)) : -1;
            const int p = pc & 1;
            *(bf16x8*)&Ks[p][strow][stc8]      = kr0;
            *(bf16x8*)&Ks[p][32 + strow][stc8] = kr1;
            if (tid < 128) mls[p][tid] = mlv;
            bf16x8 qc[2][2] = {{qan[0][0], qan[0][1]}, {qan[1][0], qan[1][1]}};
            __syncthreads();
            if (hn >= 0) load_head(hn);

            f32x4 s[2][4] = {};
#pragma unroll
            for (int kc = 0; kc < 2; ++kc) {
#pragma unroll
                for (int kt = 0; kt < 4; ++kt) {
                    bf16x8 kb = *(const bf16x8*)&Ks[p][kt * 16 + n16][kc * 32 + quad * 8];
                    s[0][kt] = mfma16(kb, qc[0][kc], s[0][kt]);
                    s[1][kt] = mfma16(kb, qc[1][kc], s[1][kt]);
                }
            }
#pragma unroll
            for (int qg = 0; qg < 2; ++qg) {
                const float ml = mls[p][w * 32 + qg * 16 + n16];
#pragma unroll
                for (int kt = 0; kt < 4; ++kt)
#pragma unroll
                    for (int r = 0; r < 4; ++r)
                        acc[qg][kt][r] += exp2f_fast(s[qg][kt][r] +
                                                     bias0[qg][kt][r] - ml);
            }
            ++pc;
            if (hn < 0) break;
            h = hn;
        }
    }

    const float invH = 1.f / (float)NHEAD;
#pragma unroll
    for (int qg = 0; qg < 2; ++qg)
#pragma unroll
        for (int kt = 0; kt < 4; ++kt) {
            f32x4 ov;
#pragma unroll
            for (int r = 0; r < 4; ++r) ov[r] = acc[qg][kt][r] * invH;
            *(f32x4*)(outmean + ((size_t)b * LL + qq[qg]) * LL + k0 +
                      kt * 16 + quad * 4) = ov;
        }
}

// ---------------------------------------------------------------------------
extern "C" void kernel_launch(void* const* d_in, const int* in_sizes, int n_in,
                              void* d_out, int out_size, void* d_ws, size_t ws_size,
                              hipStream_t stream) {
    const float* x  = (const float*)d_in[0];
    const float* dr = (const float*)d_in[1];
    const float* Wq = (const float*)d_in[2];
    const float* bq = (const float*)d_in[3];
    const float* Wk = (const float*)d_in[4];
    const float* bk = (const float*)d_in[5];
    const float* Wv = (const float*)d_in[6];
    const float* bv = (const float*)d_in[7];
    const float* Wo = (const float*)d_in[8];
    const float* bo = (const float*)d_in[9];
    float* out = (float*)d_out;
    char* ws = (char*)d_ws;
    const size_t MB = 1ull << 20;

    bf16_t* xb   = (bf16_t*)(ws);             // 8 MB; reused as ctx after QKV gemm
    bf16_t* Wcat = (bf16_t*)(ws + 8 * MB);    // 6 MB  [3072][1024]
    bf16_t* Wot  = (bf16_t*)(ws + 14 * MB);   // 2 MB
    bf16_t* Qb   = (bf16_t*)(ws + 16 * MB);   // 8 MB
    bf16_t* Kb   = (bf16_t*)(ws + 24 * MB);   // 8 MB
    bf16_t* Vtb  = (bf16_t*)(ws + 32 * MB);   // 8 MB  [b,h,dk,l]
    float*  logd = (float*)(ws + 40 * MB);    // 16 KB
    float*  mlws = (float*)(ws + 41 * MB);    // 256 KB
    float*  Qns  = (float*)(ws + 42 * MB);            // [32][16]
    float*  Kns  = (float*)(ws + 42 * MB + 4096);     // [32][32]
    float*  dlb  = (float*)(ws + 42 * MB + 12288);    // [32][16]
    float*  ldxp = (float*)(ws + 42 * MB + 16384);    // [2][32]
    float*  mlmn = (float*)(ws + 42 * MB + 20480);    // [32][16]
    bf16_t* ctx  = xb;

    prep_x_k<<<2048, 256, 0, stream>>>(x, dr, xb, logd);
    prep_w_k<<<dim3(16, 16, 4), 256, 0, stream>>>(Wq, Wk, Wv, Wo, Wcat, Wot);

    gemm128_k<<<dim3(24, 32), 256, 0, stream>>>(xb, Wcat, bq, bk, bv, dr,
                                                nullptr, Qb, Kb, Vtb, 0);
    stats_k<<<32, 256, 0, stream>>>(Qb, Kb, logd, Qns, Kns, dlb, ldxp);

    attn_flash_mfma_k<<<dim3(32, 32), 256, 0, stream>>>(Qb, Kb, Vtb, logd,
                                                        Qns, Kns, dlb, ldxp,
                                                        ctx, mlws);
    mlstat_k<<<32, 256, 0, stream>>>(mlws, mlmn);
    attn_mean_mfma_k<<<dim3(32, 16, 2), 256, 0, stream>>>(
        Qb, Kb, logd, mlws, Qns, Kns, mlmn, ldxp,
        out + (size_t)MTOT * DMODEL);
    gemm_out_k<<<dim3(8, 64), 256, 0, stream>>>(ctx, Wot, bo, out);
}